// Round 2
// baseline (9918.701 us; speedup 1.0000x reference)
//
#include <hip/hip_runtime.h>

#define N_IJKL   1000000
#define N_UIJK   500000
#define N_IJK    250000
#define N_UIJKL  2000000
#define LVL_STRIDE 4000000LL   // N_UIJK * 8 floats per level
#define NBLK_SCAN 489          // ceil(500000/1024)

// ---------------- tall-skinny GEMM: A[N,128] @ W[128,8] -> out[N,8] ----------------
__global__ __launch_bounds__(256) void k_gemm128x8(const float* __restrict__ A,
                                                   const float* __restrict__ W,
                                                   float* __restrict__ out) {
  __shared__ float sA[32][132];
  __shared__ float sW[8][132];
  const int t = threadIdx.x;
  for (int i = t; i < 1024; i += 256) sW[i & 7][i >> 3] = W[i];
  const long long r0 = (long long)blockIdx.x * 32;
  const float4* A4 = (const float4*)(A + r0 * 128);
  for (int i = t; i < 1024; i += 256) {
    float4 v = A4[i];
    ((float4*)&sA[i >> 5][0])[i & 31] = v;
  }
  __syncthreads();
  const int row = t >> 3, h = t & 7;
  float acc = 0.f;
  #pragma unroll
  for (int c4 = 0; c4 < 32; ++c4) {
    float4 a = ((const float4*)&sA[row][0])[c4];
    float4 w = ((const float4*)&sW[h][0])[c4];
    acc = fmaf(a.x, w.x, acc); acc = fmaf(a.y, w.y, acc);
    acc = fmaf(a.z, w.z, acc); acc = fmaf(a.w, w.w, acc);
  }
  out[(r0 + row) * 8 + h] = acc;
}

__device__ __forceinline__ unsigned flip_f32(float x) {
  unsigned u = __float_as_uint(x);
  return (u & 0x80000000u) ? ~u : (u | 0x80000000u);
}
__device__ __forceinline__ float unflip_f32(unsigned u) {
  return __uint_as_float((u & 0x80000000u) ? (u & 0x7FFFFFFFu) : ~u);
}

__global__ __launch_bounds__(256) void k_segmax(const float* __restrict__ tpk,
                                                const int* __restrict__ seg,
                                                unsigned* __restrict__ mu) {
  int i = blockIdx.x * 256 + threadIdx.x;
  if (i >= N_IJKL) return;
  int sg = seg[i];
  const float4* r = (const float4*)(tpk + (long long)i * 8);
  float4 a = r[0], b = r[1];
  float v[8] = {a.x, a.y, a.z, a.w, b.x, b.y, b.z, b.w};
  unsigned* m = mu + (long long)sg * 8;
  #pragma unroll
  for (int h = 0; h < 8; ++h) atomicMax(&m[h], flip_f32(v[h]));
}

__global__ __launch_bounds__(256) void k_expsum(float* __restrict__ tpk,
                                                const int* __restrict__ seg,
                                                const unsigned* __restrict__ mu,
                                                float* __restrict__ s) {
  int i = blockIdx.x * 256 + threadIdx.x;
  if (i >= N_IJKL) return;
  int sg = seg[i];
  float4* r = (float4*)(tpk + (long long)i * 8);
  float4 a = r[0], b = r[1];
  const unsigned* m = mu + (long long)sg * 8;
  float v[8] = {a.x, a.y, a.z, a.w, b.x, b.y, b.z, b.w};
  float e[8];
  float* sp = s + (long long)sg * 8;
  #pragma unroll
  for (int h = 0; h < 8; ++h) {
    e[h] = expf(v[h] - unflip_f32(m[h]));
    atomicAdd(&sp[h], e[h]);
  }
  r[0] = make_float4(e[0], e[1], e[2], e[3]);
  r[1] = make_float4(e[4], e[5], e[6], e[7]);
}

__global__ __launch_bounds__(256) void k_div(float* __restrict__ tpk,
                                             const int* __restrict__ seg,
                                             const float* __restrict__ s) {
  int i = blockIdx.x * 256 + threadIdx.x;
  if (i >= N_IJKL) return;
  int sg = seg[i];
  float4* r = (float4*)(tpk + (long long)i * 8);
  const float4* sp = (const float4*)(s + (long long)sg * 8);
  float4 a = r[0], b = r[1];
  float4 s0 = sp[0], s1 = sp[1];
  a.x /= s0.x; a.y /= s0.y; a.z /= s0.z; a.w /= s0.w;
  b.x /= s1.x; b.y /= s1.y; b.z /= s1.z; b.w /= s1.w;
  r[0] = a; r[1] = b;
}

// ---------------- CSR build: histogram, 2-level scan, scatter ----------------
__global__ __launch_bounds__(256) void k_hist(const int* __restrict__ dst, int* __restrict__ cnt) {
  int e = blockIdx.x * 256 + threadIdx.x;
  if (e < N_UIJKL) atomicAdd(&cnt[dst[e]], 1);
}

__global__ __launch_bounds__(256) void k_scan_a(const int* __restrict__ cnt, int* __restrict__ bsum) {
  __shared__ int sd[256];
  int t = threadIdx.x;
  int i0 = blockIdx.x * 1024 + t * 4;
  int s = 0;
  #pragma unroll
  for (int k = 0; k < 4; ++k) if (i0 + k < N_UIJK) s += cnt[i0 + k];
  sd[t] = s; __syncthreads();
  for (int o = 128; o > 0; o >>= 1) {
    if (t < o) sd[t] += sd[t + o];
    __syncthreads();
  }
  if (t == 0) bsum[blockIdx.x] = sd[0];
}

__global__ __launch_bounds__(512) void k_scan_b(int* __restrict__ bsum) {
  __shared__ int sd[512];
  int t = threadIdx.x;
  int v = (t < NBLK_SCAN) ? bsum[t] : 0;
  sd[t] = v; __syncthreads();
  for (int o = 1; o < 512; o <<= 1) {
    int u = (t >= o) ? sd[t - o] : 0;
    __syncthreads();
    sd[t] += u;
    __syncthreads();
  }
  int incl = sd[t];
  if (t < NBLK_SCAN) bsum[t] = incl - v;          // exclusive
  if (t == NBLK_SCAN - 1) bsum[NBLK_SCAN] = incl; // total
}

__global__ __launch_bounds__(256) void k_scan_c(const int* __restrict__ cnt,
                                                const int* __restrict__ bsum,
                                                int* __restrict__ off,
                                                int* __restrict__ cursor) {
  __shared__ int sd[256];
  int t = threadIdx.x, blk = blockIdx.x;
  int i0 = blk * 1024 + t * 4;
  int c0 = (i0 + 0 < N_UIJK) ? cnt[i0 + 0] : 0;
  int c1 = (i0 + 1 < N_UIJK) ? cnt[i0 + 1] : 0;
  int c2 = (i0 + 2 < N_UIJK) ? cnt[i0 + 2] : 0;
  int c3 = (i0 + 3 < N_UIJK) ? cnt[i0 + 3] : 0;
  int tsum = c0 + c1 + c2 + c3;
  sd[t] = tsum; __syncthreads();
  for (int o = 1; o < 256; o <<= 1) {
    int u = (t >= o) ? sd[t - o] : 0;
    __syncthreads();
    sd[t] += u;
    __syncthreads();
  }
  int base = bsum[blk] + sd[t] - tsum;
  if (i0 + 0 < N_UIJK) { off[i0 + 0] = base; cursor[i0 + 0] = base; }
  base += c0;
  if (i0 + 1 < N_UIJK) { off[i0 + 1] = base; cursor[i0 + 1] = base; }
  base += c1;
  if (i0 + 2 < N_UIJK) { off[i0 + 2] = base; cursor[i0 + 2] = base; }
  base += c2;
  if (i0 + 3 < N_UIJK) { off[i0 + 3] = base; cursor[i0 + 3] = base; }
  if (blk == 0 && t == 0) off[N_UIJK] = bsum[NBLK_SCAN];
}

__global__ __launch_bounds__(256) void k_scatter(const int* __restrict__ dst,
                                                 int* __restrict__ cursor,
                                                 int* __restrict__ perm) {
  int e = blockIdx.x * 256 + threadIdx.x;
  if (e >= N_UIJKL) return;
  int pos = atomicAdd(&cursor[dst[e]], 1);
  perm[pos] = e;
}

// kerp[pos] = alpha[aidx[perm[pos]]]
__global__ __launch_bounds__(256) void k_gatherp(const float* __restrict__ alpha,
                                                 const int* __restrict__ perm,
                                                 const int* __restrict__ aidx,
                                                 float* __restrict__ kerp) {
  int pos = blockIdx.x * 256 + threadIdx.x;
  if (pos >= N_UIJKL) return;
  int e = perm[pos];
  const float4* s4 = (const float4*)(alpha + (long long)aidx[e] * 8);
  float4* d4 = (float4*)(kerp + (long long)pos * 8);
  d4[0] = s4[0]; d4[1] = s4[1];
}

__global__ __launch_bounds__(256) void k_srcp(const int* __restrict__ perm,
                                              const int* __restrict__ gsrc,
                                              int* __restrict__ srcp) {
  int pos = blockIdx.x * 256 + threadIdx.x;
  if (pos >= N_UIJKL) return;
  srcp[pos] = gsrc[perm[pos]];
}

// ---------------- conv (CSR, no atomics): 8 lanes per dst row ----------------
__global__ __launch_bounds__(256) void k_conv(const float* __restrict__ kerp,
                                              const int* __restrict__ srcp,
                                              const int* __restrict__ off,
                                              const float* __restrict__ lin,
                                              float* __restrict__ lout) {
  int gid = blockIdx.x * 256 + threadIdx.x;
  int d = gid >> 3, h = gid & 7;
  if (d >= N_UIJK) return;
  int p0 = off[d], p1 = off[d + 1];
  float acc = 0.f;
  for (int p = p0; p < p1; ++p)
    acc = fmaf(kerp[(long long)p * 8 + h], lin[(long long)srcp[p] * 8 + h], acc);
  lout[(long long)d * 8 + h] = acc;
}

// ---------------- MLP: 128 thr, 256 rows/block, 2 rows/thread, LDS weights ----------------
__global__ __launch_bounds__(128) void k_mlp(const float* __restrict__ lvl,
                                             const float* __restrict__ prop,
                                             const float* __restrict__ W1,
                                             const float* __restrict__ b1,
                                             const float* __restrict__ W2,
                                             const float* __restrict__ b2,
                                             float* __restrict__ outp) {
  __shared__ __align__(16) float sm[6144 + 5184];  // xt[24][256] | w1s[72][72]; later w2s aliases sm
  float* xt = sm;
  float* w1s = sm + 6144;
  const int t = threadIdx.x;
  const long long r0 = (long long)blockIdx.x * 256;
  const int rA = t, rB = t + 128;

  {  // stage W1
    const float4* src = (const float4*)W1;
    float4* dst4 = (float4*)w1s;
    for (int i = t; i < 1296; i += 128) dst4[i] = src[i];
  }
  float h[2][72];
  #pragma unroll
  for (int j = 0; j < 72; ++j) { float bv = b1[j]; h[0][j] = bv; h[1][j] = bv; }

  #pragma unroll 1
  for (int ck = 0; ck < 3; ++ck) {
    __syncthreads();
    for (int i = t; i < 1536; i += 128) {   // 3 levels x 256 rows x 2 halves
      int lv = i >> 9;
      int rem = i & 511;
      int row = rem >> 1;
      int half = (rem & 1) << 2;
      long long r = r0 + row;
      float4 v = make_float4(0.f, 0.f, 0.f, 0.f);
      if (r < N_UIJK)
        v = *(const float4*)(lvl + (long long)(ck * 3 + lv) * LVL_STRIDE + r * 8 + half);
      int cl = lv * 8 + half;
      xt[(cl + 0) * 256 + row] = v.x;
      xt[(cl + 1) * 256 + row] = v.y;
      xt[(cl + 2) * 256 + row] = v.z;
      xt[(cl + 3) * 256 + row] = v.w;
    }
    __syncthreads();
    #pragma unroll 4
    for (int cl = 0; cl < 24; ++cl) {
      int c = ck * 24 + cl;
      float xa = xt[cl * 256 + rA];
      float xb = xt[cl * 256 + rB];
      const float4* wr = (const float4*)(w1s + c * 72);
      #pragma unroll
      for (int q = 0; q < 18; ++q) {
        float4 w = wr[q];
        h[0][q * 4 + 0] = fmaf(xa, w.x, h[0][q * 4 + 0]);
        h[0][q * 4 + 1] = fmaf(xa, w.y, h[0][q * 4 + 1]);
        h[0][q * 4 + 2] = fmaf(xa, w.z, h[0][q * 4 + 2]);
        h[0][q * 4 + 3] = fmaf(xa, w.w, h[0][q * 4 + 3]);
        h[1][q * 4 + 0] = fmaf(xb, w.x, h[1][q * 4 + 0]);
        h[1][q * 4 + 1] = fmaf(xb, w.y, h[1][q * 4 + 1]);
        h[1][q * 4 + 2] = fmaf(xb, w.z, h[1][q * 4 + 2]);
        h[1][q * 4 + 3] = fmaf(xb, w.w, h[1][q * 4 + 3]);
      }
    }
  }
  // exact GELU
  #pragma unroll
  for (int i = 0; i < 2; ++i)
    #pragma unroll
    for (int j = 0; j < 72; ++j) {
      float v = h[i][j];
      h[i][j] = 0.5f * v * (1.0f + erff(v * 0.70710678118654752f));
    }
  __syncthreads();
  {  // stage W2 (aliases xt+w1s region)
    const float4* src = (const float4*)W2;
    float4* dst4 = (float4*)sm;
    for (int i = t; i < 2304; i += 128) dst4[i] = src[i];
  }
  __syncthreads();
  const float* w2s = sm;
  const bool okA = (r0 + rA) < N_UIJK, okB = (r0 + rB) < N_UIJK;
  #pragma unroll 1
  for (int ch = 0; ch < 8; ++ch) {   // 16-col chunks
    float oA[16], oB[16];
    #pragma unroll
    for (int k = 0; k < 16; ++k) { float bv = b2[ch * 16 + k]; oA[k] = bv; oB[k] = bv; }
    #pragma unroll
    for (int j = 0; j < 72; ++j) {
      float ha = h[0][j], hb = h[1][j];
      const float4* wr = (const float4*)(w2s + j * 128 + ch * 16);
      #pragma unroll
      for (int q = 0; q < 4; ++q) {
        float4 w = wr[q];
        oA[q * 4 + 0] = fmaf(ha, w.x, oA[q * 4 + 0]);
        oA[q * 4 + 1] = fmaf(ha, w.y, oA[q * 4 + 1]);
        oA[q * 4 + 2] = fmaf(ha, w.z, oA[q * 4 + 2]);
        oA[q * 4 + 3] = fmaf(ha, w.w, oA[q * 4 + 3]);
        oB[q * 4 + 0] = fmaf(hb, w.x, oB[q * 4 + 0]);
        oB[q * 4 + 1] = fmaf(hb, w.y, oB[q * 4 + 1]);
        oB[q * 4 + 2] = fmaf(hb, w.z, oB[q * 4 + 2]);
        oB[q * 4 + 3] = fmaf(hb, w.w, oB[q * 4 + 3]);
      }
    }
    if (okA) {
      const float4* pr = (const float4*)(prop + (r0 + rA) * 128 + ch * 16);
      float4* po = (float4*)(outp + (r0 + rA) * 128 + ch * 16);
      #pragma unroll
      for (int q = 0; q < 4; ++q) {
        float4 pv = pr[q];
        po[q] = make_float4(oA[q * 4 + 0] + pv.x, oA[q * 4 + 1] + pv.y,
                            oA[q * 4 + 2] + pv.z, oA[q * 4 + 3] + pv.w);
      }
    }
    if (okB) {
      const float4* pr = (const float4*)(prop + (r0 + rB) * 128 + ch * 16);
      float4* po = (float4*)(outp + (r0 + rB) * 128 + ch * 16);
      #pragma unroll
      for (int q = 0; q < 4; ++q) {
        float4 pv = pr[q];
        po[q] = make_float4(oB[q * 4 + 0] + pv.x, oB[q * 4 + 1] + pv.y,
                            oB[q * 4 + 2] + pv.z, oB[q * 4 + 3] + pv.w);
      }
    }
  }
}

extern "C" void kernel_launch(void* const* d_in, const int* in_sizes, int n_in,
                              void* d_out, int out_size, void* d_ws, size_t ws_size,
                              hipStream_t stream) {
  const float* prop   = (const float*)d_in[0];
  const float* stereo = (const float*)d_in[1];
  const float* Wv     = (const float*)d_in[2];
  const float* Wk     = (const float*)d_in[3];
  const float* W1     = (const float*)d_in[4];
  const float* b1     = (const float*)d_in[5];
  const float* W2     = (const float*)d_in[6];
  const float* b2     = (const float*)d_in[7];
  const int* g_jkl    = (const int*)d_in[8];
  const int* g_U_ijkl = (const int*)d_in[9];
  const int* g_U_Uijk = (const int*)d_in[10];
  const int* g_U_ujkl = (const int*)d_in[11];

  float* ws    = (float*)d_ws;
  float* tpk   = ws;                               // [0, 8e6): tpk -> alpha
  unsigned* mu = (unsigned*)(ws + 8000000);        // [8e6,10e6) later: cnt/off/cursor/bsum
  float* s     = ws + 10000000;                    // [10e6,12e6) later: perm
  float* kerp  = ws + 12000000;                    // 16e6 permuted kernel
  float* lvl   = ws + 28000000;                    // 36e6 (9 levels)
  int* srcp    = (int*)ws;                         // 2e6 (after alpha is dead)
  int* cnt     = (int*)(ws + 8000000);             // 500k
  int* off     = (int*)(ws + 8500000);             // 500001
  int* cursor  = (int*)(ws + 9100000);             // 500k
  int* bsum    = (int*)(ws + 9700000);             // 490
  int* perm    = (int*)(ws + 10000000);            // 2e6

  hipMemsetAsync(mu, 0, 4000000 * sizeof(float), stream);   // mu + s

  k_gemm128x8<<<N_IJKL / 32, 256, 0, stream>>>(stereo, Wk, tpk);
  k_gemm128x8<<<N_UIJK / 32, 256, 0, stream>>>(prop, Wv, lvl);

  k_segmax<<<(N_IJKL + 255) / 256, 256, 0, stream>>>(tpk, g_jkl, mu);
  k_expsum<<<(N_IJKL + 255) / 256, 256, 0, stream>>>(tpk, g_jkl, mu, s);
  k_div   <<<(N_IJKL + 255) / 256, 256, 0, stream>>>(tpk, g_jkl, s);

  // CSR build (mu/s regions are dead now)
  hipMemsetAsync(cnt, 0, N_UIJK * sizeof(int), stream);
  k_hist   <<<(N_UIJKL + 255) / 256, 256, 0, stream>>>(g_U_ujkl, cnt);
  k_scan_a <<<NBLK_SCAN, 256, 0, stream>>>(cnt, bsum);
  k_scan_b <<<1, 512, 0, stream>>>(bsum);
  k_scan_c <<<NBLK_SCAN, 256, 0, stream>>>(cnt, bsum, off, cursor);
  k_scatter<<<(N_UIJKL + 255) / 256, 256, 0, stream>>>(g_U_ujkl, cursor, perm);

  k_gatherp<<<(N_UIJKL + 255) / 256, 256, 0, stream>>>(tpk, perm, g_U_ijkl, kerp);
  k_srcp   <<<(N_UIJKL + 255) / 256, 256, 0, stream>>>(perm, g_U_Uijk, srcp);

  for (int t = 0; t < 8; ++t) {
    k_conv<<<(N_UIJK * 8 + 255) / 256, 256, 0, stream>>>(
        kerp, srcp, off, lvl + t * LVL_STRIDE, lvl + (t + 1) * LVL_STRIDE);
  }

  k_mlp<<<(N_UIJK + 255) / 256, 128, 0, stream>>>(lvl, prop, W1, b1, W2, b2, (float*)d_out);
}

// Round 3
// 2117.717 us; speedup vs baseline: 4.6837x; 4.6837x over previous
//
#include <hip/hip_runtime.h>

#define N_IJKL   1000000
#define N_UIJK   500000
#define N_IJK    250000
#define N_UIJKL  2000000
#define LVL_STRIDE 4000000LL   // N_UIJK * 8 floats per level
#define NBLK_SCAN 489          // ceil(500000/1024)

// ---------------- tall-skinny GEMM: A[N,128] @ W[128,8] -> out[N,8] ----------------
__global__ __launch_bounds__(256) void k_gemm128x8(const float* __restrict__ A,
                                                   const float* __restrict__ W,
                                                   float* __restrict__ out) {
  __shared__ float sA[32][132];
  __shared__ float sW[8][132];
  const int t = threadIdx.x;
  for (int i = t; i < 1024; i += 256) sW[i & 7][i >> 3] = W[i];
  const long long r0 = (long long)blockIdx.x * 32;
  const float4* A4 = (const float4*)(A + r0 * 128);
  for (int i = t; i < 1024; i += 256) {
    float4 v = A4[i];
    ((float4*)&sA[i >> 5][0])[i & 31] = v;
  }
  __syncthreads();
  const int row = t >> 3, h = t & 7;
  float acc = 0.f;
  #pragma unroll
  for (int c4 = 0; c4 < 32; ++c4) {
    float4 a = ((const float4*)&sA[row][0])[c4];
    float4 w = ((const float4*)&sW[h][0])[c4];
    acc = fmaf(a.x, w.x, acc); acc = fmaf(a.y, w.y, acc);
    acc = fmaf(a.z, w.z, acc); acc = fmaf(a.w, w.w, acc);
  }
  out[(r0 + row) * 8 + h] = acc;
}

__device__ __forceinline__ unsigned flip_f32(float x) {
  unsigned u = __float_as_uint(x);
  return (u & 0x80000000u) ? ~u : (u | 0x80000000u);
}
__device__ __forceinline__ float unflip_f32(unsigned u) {
  return __uint_as_float((u & 0x80000000u) ? (u & 0x7FFFFFFFu) : ~u);
}

__global__ __launch_bounds__(256) void k_segmax(const float* __restrict__ tpk,
                                                const int* __restrict__ seg,
                                                unsigned* __restrict__ mu) {
  int i = blockIdx.x * 256 + threadIdx.x;
  if (i >= N_IJKL) return;
  int sg = seg[i];
  const float4* r = (const float4*)(tpk + (long long)i * 8);
  float4 a = r[0], b = r[1];
  float v[8] = {a.x, a.y, a.z, a.w, b.x, b.y, b.z, b.w};
  unsigned* m = mu + (long long)sg * 8;
  #pragma unroll
  for (int h = 0; h < 8; ++h) atomicMax(&m[h], flip_f32(v[h]));
}

__global__ __launch_bounds__(256) void k_expsum(float* __restrict__ tpk,
                                                const int* __restrict__ seg,
                                                const unsigned* __restrict__ mu,
                                                float* __restrict__ s) {
  int i = blockIdx.x * 256 + threadIdx.x;
  if (i >= N_IJKL) return;
  int sg = seg[i];
  float4* r = (float4*)(tpk + (long long)i * 8);
  float4 a = r[0], b = r[1];
  const unsigned* m = mu + (long long)sg * 8;
  float v[8] = {a.x, a.y, a.z, a.w, b.x, b.y, b.z, b.w};
  float e[8];
  float* sp = s + (long long)sg * 8;
  #pragma unroll
  for (int h = 0; h < 8; ++h) {
    e[h] = expf(v[h] - unflip_f32(m[h]));
    atomicAdd(&sp[h], e[h]);
  }
  r[0] = make_float4(e[0], e[1], e[2], e[3]);
  r[1] = make_float4(e[4], e[5], e[6], e[7]);
}

__global__ __launch_bounds__(256) void k_div(float* __restrict__ tpk,
                                             const int* __restrict__ seg,
                                             const float* __restrict__ s) {
  int i = blockIdx.x * 256 + threadIdx.x;
  if (i >= N_IJKL) return;
  int sg = seg[i];
  float4* r = (float4*)(tpk + (long long)i * 8);
  const float4* sp = (const float4*)(s + (long long)sg * 8);
  float4 a = r[0], b = r[1];
  float4 s0 = sp[0], s1 = sp[1];
  a.x /= s0.x; a.y /= s0.y; a.z /= s0.z; a.w /= s0.w;
  b.x /= s1.x; b.y /= s1.y; b.z /= s1.z; b.w /= s1.w;
  r[0] = a; r[1] = b;
}

// ---------------- CSR build ----------------
__global__ __launch_bounds__(256) void k_hist(const int* __restrict__ dst, int* __restrict__ cnt) {
  int e = blockIdx.x * 256 + threadIdx.x;
  if (e < N_UIJKL) atomicAdd(&cnt[dst[e]], 1);
}

__global__ __launch_bounds__(256) void k_scan_a(const int* __restrict__ cnt, int* __restrict__ bsum) {
  __shared__ int sd[256];
  int t = threadIdx.x;
  int i0 = blockIdx.x * 1024 + t * 4;
  int s = 0;
  #pragma unroll
  for (int k = 0; k < 4; ++k) if (i0 + k < N_UIJK) s += cnt[i0 + k];
  sd[t] = s; __syncthreads();
  for (int o = 128; o > 0; o >>= 1) {
    if (t < o) sd[t] += sd[t + o];
    __syncthreads();
  }
  if (t == 0) bsum[blockIdx.x] = sd[0];
}

__global__ __launch_bounds__(512) void k_scan_b(int* __restrict__ bsum) {
  __shared__ int sd[512];
  int t = threadIdx.x;
  int v = (t < NBLK_SCAN) ? bsum[t] : 0;
  sd[t] = v; __syncthreads();
  for (int o = 1; o < 512; o <<= 1) {
    int u = (t >= o) ? sd[t - o] : 0;
    __syncthreads();
    sd[t] += u;
    __syncthreads();
  }
  int incl = sd[t];
  if (t < NBLK_SCAN) bsum[t] = incl - v;
  if (t == NBLK_SCAN - 1) bsum[NBLK_SCAN] = incl;
}

__global__ __launch_bounds__(256) void k_scan_c(const int* __restrict__ cnt,
                                                const int* __restrict__ bsum,
                                                int* __restrict__ off,
                                                int* __restrict__ cursor) {
  __shared__ int sd[256];
  int t = threadIdx.x, blk = blockIdx.x;
  int i0 = blk * 1024 + t * 4;
  int c0 = (i0 + 0 < N_UIJK) ? cnt[i0 + 0] : 0;
  int c1 = (i0 + 1 < N_UIJK) ? cnt[i0 + 1] : 0;
  int c2 = (i0 + 2 < N_UIJK) ? cnt[i0 + 2] : 0;
  int c3 = (i0 + 3 < N_UIJK) ? cnt[i0 + 3] : 0;
  int tsum = c0 + c1 + c2 + c3;
  sd[t] = tsum; __syncthreads();
  for (int o = 1; o < 256; o <<= 1) {
    int u = (t >= o) ? sd[t - o] : 0;
    __syncthreads();
    sd[t] += u;
    __syncthreads();
  }
  int base = bsum[blk] + sd[t] - tsum;
  if (i0 + 0 < N_UIJK) { off[i0 + 0] = base; cursor[i0 + 0] = base; }
  base += c0;
  if (i0 + 1 < N_UIJK) { off[i0 + 1] = base; cursor[i0 + 1] = base; }
  base += c1;
  if (i0 + 2 < N_UIJK) { off[i0 + 2] = base; cursor[i0 + 2] = base; }
  base += c2;
  if (i0 + 3 < N_UIJK) { off[i0 + 3] = base; cursor[i0 + 3] = base; }
  if (blk == 0 && t == 0) off[N_UIJK] = bsum[NBLK_SCAN];
}

__global__ __launch_bounds__(256) void k_scatter(const int* __restrict__ dst,
                                                 int* __restrict__ cursor,
                                                 int* __restrict__ perm) {
  int e = blockIdx.x * 256 + threadIdx.x;
  if (e >= N_UIJKL) return;
  int pos = atomicAdd(&cursor[dst[e]], 1);
  perm[pos] = e;
}

__global__ __launch_bounds__(256) void k_gatherp(const float* __restrict__ alpha,
                                                 const int* __restrict__ perm,
                                                 const int* __restrict__ aidx,
                                                 float* __restrict__ kerp) {
  int pos = blockIdx.x * 256 + threadIdx.x;
  if (pos >= N_UIJKL) return;
  int e = perm[pos];
  const float4* s4 = (const float4*)(alpha + (long long)aidx[e] * 8);
  float4* d4 = (float4*)(kerp + (long long)pos * 8);
  d4[0] = s4[0]; d4[1] = s4[1];
}

__global__ __launch_bounds__(256) void k_srcp(const int* __restrict__ perm,
                                              const int* __restrict__ gsrc,
                                              int* __restrict__ srcp) {
  int pos = blockIdx.x * 256 + threadIdx.x;
  if (pos >= N_UIJKL) return;
  srcp[pos] = gsrc[perm[pos]];
}

// ---------------- conv (CSR, no atomics): 8 lanes per dst row ----------------
__global__ __launch_bounds__(256) void k_conv(const float* __restrict__ kerp,
                                              const int* __restrict__ srcp,
                                              const int* __restrict__ off,
                                              const float* __restrict__ lin,
                                              float* __restrict__ lout) {
  int gid = blockIdx.x * 256 + threadIdx.x;
  int d = gid >> 3, h = gid & 7;
  if (d >= N_UIJK) return;
  int p0 = off[d], p1 = off[d + 1];
  float acc = 0.f;
  for (int p = p0; p < p1; ++p)
    acc = fmaf(kerp[(long long)p * 8 + h], lin[(long long)srcp[p] * 8 + h], acc);
  lout[(long long)d * 8 + h] = acc;
}

// ---------------- fused MLP: 1 row/thread, h[72] in regs, x streamed ----------------
__global__ __launch_bounds__(256) void k_mlp(const float* __restrict__ lvl,
                                             const float* __restrict__ prop,
                                             const float* __restrict__ W1,
                                             const float* __restrict__ b1,
                                             const float* __restrict__ W2,
                                             const float* __restrict__ b2,
                                             float* __restrict__ outp) {
  const long long r = (long long)blockIdx.x * 256 + threadIdx.x;
  if (r >= N_UIJK) return;

  float h[72];
  #pragma unroll
  for (int j = 0; j < 72; ++j) h[j] = b1[j];

  // phase 1: h += x @ W1, x streamed 8 floats (one level) at a time
  #pragma unroll 1
  for (int t = 0; t < 9; ++t) {
    const float4* xp = (const float4*)(lvl + (long long)t * LVL_STRIDE + r * 8);
    float4 xa = xp[0], xb = xp[1];
    float xlv[8] = {xa.x, xa.y, xa.z, xa.w, xb.x, xb.y, xb.z, xb.w};
    const float* w1t = W1 + t * 8 * 72;
    #pragma unroll
    for (int k = 0; k < 8; ++k) {
      float xv = xlv[k];
      const float* wr = w1t + k * 72;
      #pragma unroll
      for (int j = 0; j < 72; ++j) h[j] = fmaf(xv, wr[j], h[j]);
    }
  }
  // exact GELU
  #pragma unroll
  for (int j = 0; j < 72; ++j) {
    float v = h[j];
    h[j] = 0.5f * v * (1.0f + erff(v * 0.70710678118654752f));
  }
  // phase 2: out = h @ W2 + b2 + prop, 16-col chunks
  const float4* pr = (const float4*)(prop + r * 128);
  float4* po = (float4*)(outp + r * 128);
  #pragma unroll 1
  for (int ch = 0; ch < 8; ++ch) {
    float o[16];
    #pragma unroll
    for (int k = 0; k < 16; ++k) o[k] = b2[ch * 16 + k];
    #pragma unroll
    for (int j = 0; j < 72; ++j) {
      float hv = h[j];
      const float* wr = W2 + j * 128 + ch * 16;
      #pragma unroll
      for (int k = 0; k < 16; ++k) o[k] = fmaf(hv, wr[k], o[k]);
    }
    #pragma unroll
    for (int q = 0; q < 4; ++q) {
      float4 pv = pr[ch * 4 + q];
      po[ch * 4 + q] = make_float4(o[q * 4 + 0] + pv.x, o[q * 4 + 1] + pv.y,
                                   o[q * 4 + 2] + pv.z, o[q * 4 + 3] + pv.w);
    }
  }
}

extern "C" void kernel_launch(void* const* d_in, const int* in_sizes, int n_in,
                              void* d_out, int out_size, void* d_ws, size_t ws_size,
                              hipStream_t stream) {
  const float* prop   = (const float*)d_in[0];
  const float* stereo = (const float*)d_in[1];
  const float* Wv     = (const float*)d_in[2];
  const float* Wk     = (const float*)d_in[3];
  const float* W1     = (const float*)d_in[4];
  const float* b1     = (const float*)d_in[5];
  const float* W2     = (const float*)d_in[6];
  const float* b2     = (const float*)d_in[7];
  const int* g_jkl    = (const int*)d_in[8];
  const int* g_U_ijkl = (const int*)d_in[9];
  const int* g_U_Uijk = (const int*)d_in[10];
  const int* g_U_ujkl = (const int*)d_in[11];

  float* ws    = (float*)d_ws;
  float* tpk   = ws;                               // [0, 8e6): tpk -> alpha
  unsigned* mu = (unsigned*)(ws + 8000000);
  float* s     = ws + 10000000;
  float* kerp  = ws + 12000000;                    // 16e6 permuted kernel
  float* lvl   = ws + 28000000;                    // 36e6 (9 levels)
  int* srcp    = (int*)ws;                         // reuses alpha region after it's dead
  int* cnt     = (int*)(ws + 8000000);
  int* off     = (int*)(ws + 8500000);
  int* cursor  = (int*)(ws + 9100000);
  int* bsum    = (int*)(ws + 9700000);
  int* perm    = (int*)(ws + 10000000);

  hipMemsetAsync(mu, 0, 4000000 * sizeof(float), stream);   // mu + s

  k_gemm128x8<<<N_IJKL / 32, 256, 0, stream>>>(stereo, Wk, tpk);
  k_gemm128x8<<<N_UIJK / 32, 256, 0, stream>>>(prop, Wv, lvl);

  k_segmax<<<(N_IJKL + 255) / 256, 256, 0, stream>>>(tpk, g_jkl, mu);
  k_expsum<<<(N_IJKL + 255) / 256, 256, 0, stream>>>(tpk, g_jkl, mu, s);
  k_div   <<<(N_IJKL + 255) / 256, 256, 0, stream>>>(tpk, g_jkl, s);

  hipMemsetAsync(cnt, 0, N_UIJK * sizeof(int), stream);
  k_hist   <<<(N_UIJKL + 255) / 256, 256, 0, stream>>>(g_U_ujkl, cnt);
  k_scan_a <<<NBLK_SCAN, 256, 0, stream>>>(cnt, bsum);
  k_scan_b <<<1, 512, 0, stream>>>(bsum);
  k_scan_c <<<NBLK_SCAN, 256, 0, stream>>>(cnt, bsum, off, cursor);
  k_scatter<<<(N_UIJKL + 255) / 256, 256, 0, stream>>>(g_U_ujkl, cursor, perm);

  k_gatherp<<<(N_UIJKL + 255) / 256, 256, 0, stream>>>(tpk, perm, g_U_ijkl, kerp);
  k_srcp   <<<(N_UIJKL + 255) / 256, 256, 0, stream>>>(perm, g_U_Uijk, srcp);

  for (int t = 0; t < 8; ++t) {
    k_conv<<<(N_UIJK * 8 + 255) / 256, 256, 0, stream>>>(
        kerp, srcp, off, lvl + t * LVL_STRIDE, lvl + (t + 1) * LVL_STRIDE);
  }

  k_mlp<<<(N_UIJK + 255) / 256, 256, 0, stream>>>(lvl, prop, W1, b1, W2, b2, (float*)d_out);
}

// Round 4
// 1577.579 us; speedup vs baseline: 6.2873x; 1.3424x over previous
//
#include <hip/hip_runtime.h>

#define N_IJKL   1000000
#define N_UIJK   500000
#define N_IJK    250000
#define N_UIJKL  2000000
#define LVL_STRIDE 4000000LL   // N_UIJK * 8 floats per level

// ---------------- tall-skinny GEMM: A[N,128] @ W[128,8] -> out[N,8] ----------------
__global__ __launch_bounds__(256) void k_gemm128x8(const float* __restrict__ A,
                                                   const float* __restrict__ W,
                                                   float* __restrict__ out) {
  __shared__ float sA[32][132];
  __shared__ float sW[8][132];
  const int t = threadIdx.x;
  for (int i = t; i < 1024; i += 256) sW[i & 7][i >> 3] = W[i];
  const long long r0 = (long long)blockIdx.x * 32;
  const float4* A4 = (const float4*)(A + r0 * 128);
  for (int i = t; i < 1024; i += 256) {
    float4 v = A4[i];
    ((float4*)&sA[i >> 5][0])[i & 31] = v;
  }
  __syncthreads();
  const int row = t >> 3, h = t & 7;
  float acc = 0.f;
  #pragma unroll
  for (int c4 = 0; c4 < 32; ++c4) {
    float4 a = ((const float4*)&sA[row][0])[c4];
    float4 w = ((const float4*)&sW[h][0])[c4];
    acc = fmaf(a.x, w.x, acc); acc = fmaf(a.y, w.y, acc);
    acc = fmaf(a.z, w.z, acc); acc = fmaf(a.w, w.w, acc);
  }
  out[(r0 + row) * 8 + h] = acc;
}

// ---------------- generic CSR build: histogram, 2-level scan, scatter ----------------
__global__ __launch_bounds__(256) void k_hist(const int* __restrict__ idx, int n,
                                              int* __restrict__ cnt) {
  int e = blockIdx.x * 256 + threadIdx.x;
  if (e < n) atomicAdd(&cnt[idx[e]], 1);
}

__global__ __launch_bounds__(256) void k_scan_a(const int* __restrict__ cnt, int n,
                                                int* __restrict__ bsum) {
  __shared__ int sd[256];
  int t = threadIdx.x;
  int i0 = blockIdx.x * 1024 + t * 4;
  int s = 0;
  #pragma unroll
  for (int k = 0; k < 4; ++k) if (i0 + k < n) s += cnt[i0 + k];
  sd[t] = s; __syncthreads();
  for (int o = 128; o > 0; o >>= 1) {
    if (t < o) sd[t] += sd[t + o];
    __syncthreads();
  }
  if (t == 0) bsum[blockIdx.x] = sd[0];
}

__global__ __launch_bounds__(512) void k_scan_b(int* __restrict__ bsum, int nblk) {
  __shared__ int sd[512];
  int t = threadIdx.x;
  int v = (t < nblk) ? bsum[t] : 0;
  sd[t] = v; __syncthreads();
  for (int o = 1; o < 512; o <<= 1) {
    int u = (t >= o) ? sd[t - o] : 0;
    __syncthreads();
    sd[t] += u;
    __syncthreads();
  }
  int incl = sd[t];
  if (t < nblk) bsum[t] = incl - v;          // exclusive
  if (t == nblk - 1) bsum[nblk] = incl;      // total
}

__global__ __launch_bounds__(256) void k_scan_c(const int* __restrict__ cnt, int n,
                                                const int* __restrict__ bsum, int nblk,
                                                int* __restrict__ off,
                                                int* __restrict__ cursor) {
  __shared__ int sd[256];
  int t = threadIdx.x, blk = blockIdx.x;
  int i0 = blk * 1024 + t * 4;
  int c0 = (i0 + 0 < n) ? cnt[i0 + 0] : 0;
  int c1 = (i0 + 1 < n) ? cnt[i0 + 1] : 0;
  int c2 = (i0 + 2 < n) ? cnt[i0 + 2] : 0;
  int c3 = (i0 + 3 < n) ? cnt[i0 + 3] : 0;
  int tsum = c0 + c1 + c2 + c3;
  sd[t] = tsum; __syncthreads();
  for (int o = 1; o < 256; o <<= 1) {
    int u = (t >= o) ? sd[t - o] : 0;
    __syncthreads();
    sd[t] += u;
    __syncthreads();
  }
  int base = bsum[blk] + sd[t] - tsum;
  if (i0 + 0 < n) { off[i0 + 0] = base; cursor[i0 + 0] = base; }
  base += c0;
  if (i0 + 1 < n) { off[i0 + 1] = base; cursor[i0 + 1] = base; }
  base += c1;
  if (i0 + 2 < n) { off[i0 + 2] = base; cursor[i0 + 2] = base; }
  base += c2;
  if (i0 + 3 < n) { off[i0 + 3] = base; cursor[i0 + 3] = base; }
  if (blk == 0 && t == 0) off[n] = bsum[nblk];
}

__global__ __launch_bounds__(256) void k_scatter(const int* __restrict__ idx, int n,
                                                 int* __restrict__ cursor,
                                                 int* __restrict__ perm) {
  int e = blockIdx.x * 256 + threadIdx.x;
  if (e >= n) return;
  int pos = atomicAdd(&cursor[idx[e]], 1);
  perm[pos] = e;
}

// ---------------- segment max + 1/sum(exp) via CSR (no atomics) ----------------
__global__ __launch_bounds__(256) void k_seg_ms(const float* __restrict__ tpk,
                                                const int* __restrict__ perm,
                                                const int* __restrict__ off,
                                                int nseg,
                                                float* __restrict__ m_out,
                                                float* __restrict__ rs_out) {
  int gid = blockIdx.x * 256 + threadIdx.x;
  int d = gid >> 3, h = gid & 7;
  if (d >= nseg) return;
  int p0 = off[d], p1 = off[d + 1];
  float m = -3.402823466e38f;
  for (int p = p0; p < p1; ++p)
    m = fmaxf(m, tpk[(long long)perm[p] * 8 + h]);
  float s = 0.f;
  for (int p = p0; p < p1; ++p)
    s += expf(tpk[(long long)perm[p] * 8 + h] - m);
  m_out[(long long)d * 8 + h] = m;
  rs_out[(long long)d * 8 + h] = 1.0f / s;
}

// ---------------- alpha = exp(tpk - m[seg]) * rs[seg]  (in place, coalesced) ----------------
__global__ __launch_bounds__(256) void k_alpha(float* __restrict__ tpk,
                                               const int* __restrict__ seg,
                                               const float* __restrict__ m,
                                               const float* __restrict__ rs) {
  int i = blockIdx.x * 256 + threadIdx.x;
  if (i >= N_IJKL) return;
  int sg = seg[i];
  float4* r = (float4*)(tpk + (long long)i * 8);
  const float4* mp = (const float4*)(m + (long long)sg * 8);
  const float4* rp = (const float4*)(rs + (long long)sg * 8);
  float4 a = r[0], b = r[1];
  float4 m0 = mp[0], m1 = mp[1];
  float4 q0 = rp[0], q1 = rp[1];
  a.x = expf(a.x - m0.x) * q0.x; a.y = expf(a.y - m0.y) * q0.y;
  a.z = expf(a.z - m0.z) * q0.z; a.w = expf(a.w - m0.w) * q0.w;
  b.x = expf(b.x - m1.x) * q1.x; b.y = expf(b.y - m1.y) * q1.y;
  b.z = expf(b.z - m1.z) * q1.z; b.w = expf(b.w - m1.w) * q1.w;
  r[0] = a; r[1] = b;
}

// kerp[pos] = alpha[aidx[perm[pos]]]
__global__ __launch_bounds__(256) void k_gatherp(const float* __restrict__ alpha,
                                                 const int* __restrict__ perm,
                                                 const int* __restrict__ aidx,
                                                 float* __restrict__ kerp) {
  int pos = blockIdx.x * 256 + threadIdx.x;
  if (pos >= N_UIJKL) return;
  int e = perm[pos];
  const float4* s4 = (const float4*)(alpha + (long long)aidx[e] * 8);
  float4* d4 = (float4*)(kerp + (long long)pos * 8);
  d4[0] = s4[0]; d4[1] = s4[1];
}

__global__ __launch_bounds__(256) void k_srcp(const int* __restrict__ perm,
                                              const int* __restrict__ gsrc,
                                              int* __restrict__ srcp) {
  int pos = blockIdx.x * 256 + threadIdx.x;
  if (pos >= N_UIJKL) return;
  srcp[pos] = gsrc[perm[pos]];
}

// ---------------- conv (CSR, no atomics): 8 lanes per dst row ----------------
__global__ __launch_bounds__(256) void k_conv(const float* __restrict__ kerp,
                                              const int* __restrict__ srcp,
                                              const int* __restrict__ off,
                                              const float* __restrict__ lin,
                                              float* __restrict__ lout) {
  int gid = blockIdx.x * 256 + threadIdx.x;
  int d = gid >> 3, h = gid & 7;
  if (d >= N_UIJK) return;
  int p0 = off[d], p1 = off[d + 1];
  float acc = 0.f;
  for (int p = p0; p < p1; ++p)
    acc = fmaf(kerp[(long long)p * 8 + h], lin[(long long)srcp[p] * 8 + h], acc);
  lout[(long long)d * 8 + h] = acc;
}

// ---------------- fused MLP: 1 row/thread, h[72] in regs, x streamed ----------------
__global__ __launch_bounds__(256) void k_mlp(const float* __restrict__ lvl,
                                             const float* __restrict__ prop,
                                             const float* __restrict__ W1,
                                             const float* __restrict__ b1,
                                             const float* __restrict__ W2,
                                             const float* __restrict__ b2,
                                             float* __restrict__ outp) {
  const long long r = (long long)blockIdx.x * 256 + threadIdx.x;
  if (r >= N_UIJK) return;

  float h[72];
  #pragma unroll
  for (int j = 0; j < 72; ++j) h[j] = b1[j];

  #pragma unroll 1
  for (int t = 0; t < 9; ++t) {
    const float4* xp = (const float4*)(lvl + (long long)t * LVL_STRIDE + r * 8);
    float4 xa = xp[0], xb = xp[1];
    float xlv[8] = {xa.x, xa.y, xa.z, xa.w, xb.x, xb.y, xb.z, xb.w};
    const float* w1t = W1 + t * 8 * 72;
    #pragma unroll
    for (int k = 0; k < 8; ++k) {
      float xv = xlv[k];
      const float* wr = w1t + k * 72;
      #pragma unroll
      for (int j = 0; j < 72; ++j) h[j] = fmaf(xv, wr[j], h[j]);
    }
  }
  #pragma unroll
  for (int j = 0; j < 72; ++j) {
    float v = h[j];
    h[j] = 0.5f * v * (1.0f + erff(v * 0.70710678118654752f));
  }
  const float4* pr = (const float4*)(prop + r * 128);
  float4* po = (float4*)(outp + r * 128);
  #pragma unroll 1
  for (int ch = 0; ch < 8; ++ch) {
    float o[16];
    #pragma unroll
    for (int k = 0; k < 16; ++k) o[k] = b2[ch * 16 + k];
    #pragma unroll
    for (int j = 0; j < 72; ++j) {
      float hv = h[j];
      const float* wr = W2 + j * 128 + ch * 16;
      #pragma unroll
      for (int k = 0; k < 16; ++k) o[k] = fmaf(hv, wr[k], o[k]);
    }
    #pragma unroll
    for (int q = 0; q < 4; ++q) {
      float4 pv = pr[ch * 4 + q];
      po[ch * 4 + q] = make_float4(o[q * 4 + 0] + pv.x, o[q * 4 + 1] + pv.y,
                                   o[q * 4 + 2] + pv.z, o[q * 4 + 3] + pv.w);
    }
  }
}

extern "C" void kernel_launch(void* const* d_in, const int* in_sizes, int n_in,
                              void* d_out, int out_size, void* d_ws, size_t ws_size,
                              hipStream_t stream) {
  const float* prop   = (const float*)d_in[0];
  const float* stereo = (const float*)d_in[1];
  const float* Wv     = (const float*)d_in[2];
  const float* Wk     = (const float*)d_in[3];
  const float* W1     = (const float*)d_in[4];
  const float* b1     = (const float*)d_in[5];
  const float* W2     = (const float*)d_in[6];
  const float* b2     = (const float*)d_in[7];
  const int* g_jkl    = (const int*)d_in[8];
  const int* g_U_ijkl = (const int*)d_in[9];
  const int* g_U_Uijk = (const int*)d_in[10];
  const int* g_U_ujkl = (const int*)d_in[11];

  float* ws    = (float*)d_ws;
  // layout (float offsets):
  //   tpk/alpha [0,8e6) -> later srcp [0,2e6)
  //   cnt [8.0e6,8.6e6) | off [8.6e6,9.2e6) | cursor [9.2e6,9.8e6) | bsum [9.8e6,+513)
  //   perm [10e6,12e6)  (CSR2 then CSR1, sequential reuse)
  //   m [12e6,14e6), rs [14e6,16e6)  (dead before kerp written)
  //   kerp [12e6,28e6) | lvl [28e6,64e6)
  float* tpk   = ws;
  int* cnt     = (int*)(ws + 8000000);
  int* off     = (int*)(ws + 8600000);
  int* cursor  = (int*)(ws + 9200000);
  int* bsum    = (int*)(ws + 9800000);
  int* perm    = (int*)(ws + 10000000);
  float* m     = ws + 12000000;
  float* rs    = ws + 14000000;
  float* kerp  = ws + 12000000;
  float* lvl   = ws + 28000000;
  int* srcp    = (int*)ws;

  k_gemm128x8<<<N_IJKL / 32, 256, 0, stream>>>(stereo, Wk, tpk);
  k_gemm128x8<<<N_UIJK / 32, 256, 0, stream>>>(prop, Wv, lvl);

  // ---- CSR2: 1M ijkl edges -> 250k jkl segments; segment softmax without atomics
  const int nb2 = (N_IJK + 1023) / 1024;    // 245
  hipMemsetAsync(cnt, 0, N_IJK * sizeof(int), stream);
  k_hist   <<<(N_IJKL + 255) / 256, 256, 0, stream>>>(g_jkl, N_IJKL, cnt);
  k_scan_a <<<nb2, 256, 0, stream>>>(cnt, N_IJK, bsum);
  k_scan_b <<<1, 512, 0, stream>>>(bsum, nb2);
  k_scan_c <<<nb2, 256, 0, stream>>>(cnt, N_IJK, bsum, nb2, off, cursor);
  k_scatter<<<(N_IJKL + 255) / 256, 256, 0, stream>>>(g_jkl, N_IJKL, cursor, perm);

  k_seg_ms <<<(N_IJK * 8 + 255) / 256, 256, 0, stream>>>(tpk, perm, off, N_IJK, m, rs);
  k_alpha  <<<(N_IJKL + 255) / 256, 256, 0, stream>>>(tpk, g_jkl, m, rs);

  // ---- CSR1: 2M Uijkl edges -> 500k Uijk destinations (conv scatter elimination)
  const int nb1 = (N_UIJK + 1023) / 1024;   // 489
  hipMemsetAsync(cnt, 0, N_UIJK * sizeof(int), stream);
  k_hist   <<<(N_UIJKL + 255) / 256, 256, 0, stream>>>(g_U_ujkl, N_UIJKL, cnt);
  k_scan_a <<<nb1, 256, 0, stream>>>(cnt, N_UIJK, bsum);
  k_scan_b <<<1, 512, 0, stream>>>(bsum, nb1);
  k_scan_c <<<nb1, 256, 0, stream>>>(cnt, N_UIJK, bsum, nb1, off, cursor);
  k_scatter<<<(N_UIJKL + 255) / 256, 256, 0, stream>>>(g_U_ujkl, N_UIJKL, cursor, perm);

  k_gatherp<<<(N_UIJKL + 255) / 256, 256, 0, stream>>>(tpk, perm, g_U_ijkl, kerp);
  k_srcp   <<<(N_UIJKL + 255) / 256, 256, 0, stream>>>(perm, g_U_Uijk, srcp);

  for (int t = 0; t < 8; ++t) {
    k_conv<<<(N_UIJK * 8 + 255) / 256, 256, 0, stream>>>(
        kerp, srcp, off, lvl + t * LVL_STRIDE, lvl + (t + 1) * LVL_STRIDE);
  }

  k_mlp<<<(N_UIJK + 255) / 256, 256, 0, stream>>>(lvl, prop, W1, b1, W2, b2, (float*)d_out);
}